// Round 12
// baseline (2638.520 us; speedup 1.0000x reference)
//
#include <hip/hip_runtime.h>
#include <cstddef>

#define NBLK 256
#define NTH  131072   // NBLK * 512

// ---------------- numerics helpers (mirror reference FP32 op order) ----------------

__device__ __forceinline__ float sqd(float x, float y, float z, float qx, float qy, float qz) {
#pragma clang fp contract(off)
    float dx = x - qx, dy = y - qy, dz = z - qz;
    return (dx * dx + dy * dy) + dz * dz;
}

__device__ __forceinline__ float sum3sq(float x, float y, float z) {
#pragma clang fp contract(off)
    return (x * x + y * y) + z * z;
}

__device__ __forceinline__ float sqd_dot(float ax, float ay, float az, float sa_,
                                         float bx, float by, float bz) {
#pragma clang fp contract(off)
    float sb = (bx * bx + by * by) + bz * bz;
    float dt = (ax * bx + ay * by) + az * bz;
    return (sa_ + sb) - 2.0f * dt;
}

// packed argmax key: (float bits of val << 32) | ~orig. mind >= 0 -> monotonic;
// max key == (val desc, orig asc) == reference first-occurrence argmax.
__device__ __forceinline__ unsigned long long packkey(float v, int orig) {
    return ((unsigned long long)__float_as_uint(v) << 32) | (unsigned)(~orig);
}

// ---------------- FPS large: R6-proven bucket pruning, writes gathered coords ----------

__global__ __launch_bounds__(512) void fps_sub(const float* __restrict__ xyz,
                                               float4* __restrict__ SPall,
                                               float* __restrict__ gout) {
    const int b = blockIdx.x, t = threadIdx.x, w = t >> 6, l = t & 63;
    const float* __restrict__ P = xyz + (size_t)b * 32768 * 3;
    float4* __restrict__ SP = SPall + (size_t)b * 32768;

    __shared__ float mind[32768];
    __shared__ int   cntS[512], offS[512], curS[512];
    __shared__ unsigned long long bkeyS[512];
    __shared__ float bxS[512], byS[512], bzS[512];
    __shared__ unsigned long long candK[8];
    __shared__ int   candB[8];
    __shared__ float bbS[6];
    __shared__ float scr[48];
    __shared__ int   qcntS;

    float mnx = 1e30f, mny = 1e30f, mnz = 1e30f;
    float mxx = -1e30f, mxy = -1e30f, mxz = -1e30f;
    for (int p = t; p < 32768; p += 512) {
        const float x = P[3 * p], y = P[3 * p + 1], z = P[3 * p + 2];
        mnx = fminf(mnx, x); mxx = fmaxf(mxx, x);
        mny = fminf(mny, y); mxy = fmaxf(mxy, y);
        mnz = fminf(mnz, z); mxz = fmaxf(mxz, z);
    }
#pragma unroll
    for (int o = 1; o < 64; o <<= 1) {
        mnx = fminf(mnx, __shfl_xor(mnx, o)); mxx = fmaxf(mxx, __shfl_xor(mxx, o));
        mny = fminf(mny, __shfl_xor(mny, o)); mxy = fmaxf(mxy, __shfl_xor(mxy, o));
        mnz = fminf(mnz, __shfl_xor(mnz, o)); mxz = fmaxf(mxz, __shfl_xor(mxz, o));
    }
    if (l == 0) {
        scr[w] = mnx; scr[8 + w] = mny; scr[16 + w] = mnz;
        scr[24 + w] = mxx; scr[32 + w] = mxy; scr[40 + w] = mxz;
    }
    __syncthreads();
    if (t == 0) {
        float a0 = 1e30f, a1 = 1e30f, a2 = 1e30f, a3 = -1e30f, a4 = -1e30f, a5 = -1e30f;
        for (int i = 0; i < 8; ++i) {
            a0 = fminf(a0, scr[i]);      a1 = fminf(a1, scr[8 + i]);
            a2 = fminf(a2, scr[16 + i]); a3 = fmaxf(a3, scr[24 + i]);
            a4 = fmaxf(a4, scr[32 + i]); a5 = fmaxf(a5, scr[40 + i]);
        }
        bbS[0] = a0; bbS[1] = a1; bbS[2] = a2; bbS[3] = a3; bbS[4] = a4; bbS[5] = a5;
        qcntS = 0;
    }
    __syncthreads();
    const float bx0 = bbS[0], by0 = bbS[1], bz0 = bbS[2];
    const float ex = bbS[3] - bx0, ey = bbS[4] - by0, ez = bbS[5] - bz0;
    const float ivx = ex > 1e-20f ? 8.0f / ex : 0.0f;
    const float ivy = ey > 1e-20f ? 8.0f / ey : 0.0f;
    const float ivz = ez > 1e-20f ? 8.0f / ez : 0.0f;

    cntS[t] = 0;
    __syncthreads();
    for (int p = t; p < 32768; p += 512) {
        const float x = P[3 * p], y = P[3 * p + 1], z = P[3 * p + 2];
        const int ix = min(7, (int)((x - bx0) * ivx));
        const int iy = min(7, (int)((y - by0) * ivy));
        const int iz = min(7, (int)((z - bz0) * ivz));
        atomicAdd(&cntS[(iz * 8 + iy) * 8 + ix], 1);
    }
    __syncthreads();

    offS[t] = cntS[t];
    __syncthreads();
    for (int d = 1; d < 512; d <<= 1) {
        const int v = (t >= d) ? offS[t - d] : 0;
        __syncthreads();
        offS[t] += v;
        __syncthreads();
    }
    const int myexc = offS[t] - cntS[t];
    offS[t] = myexc;
    curS[t] = myexc;
    __syncthreads();

    for (int p = t; p < 32768; p += 512) {
        const float x = P[3 * p], y = P[3 * p + 1], z = P[3 * p + 2];
        const int ix = min(7, (int)((x - bx0) * ivx));
        const int iy = min(7, (int)((y - by0) * ivy));
        const int iz = min(7, (int)((z - bz0) * ivz));
        const int pos = atomicAdd(&curS[(iz * 8 + iy) * 8 + ix], 1);
        SP[pos] = make_float4(x, y, z, __int_as_float(p));
    }
    for (int s = t; s < 32768; s += 512) mind[s] = 1e30f;
    const int myCnt = cntS[t];
    bkeyS[t] = (myCnt > 0) ? packkey(1e30f, 0x7fffffff) : 0ull;
    bxS[t] = 0.f; byS[t] = 0.f; bzS[t] = 0.f;
    if (t == 0) {
        gout[(size_t)b * 512 * 3 + 0] = P[0];
        gout[(size_t)b * 512 * 3 + 1] = P[1];
        gout[(size_t)b * 512 * 3 + 2] = P[2];
    }

    const int oix = t & 7, oiy = (t >> 3) & 7, oiz = t >> 6;
    const float gwx = ex * 0.125f, gwy = ey * 0.125f, gwz = ez * 0.125f;
    const float x0o = bx0 + oix * gwx, x1o = x0o + gwx;
    const float y0o = by0 + oiy * gwy, y1o = y0o + gwy;
    const float z0o = bz0 + oiz * gwz, z1o = z0o + gwz;

    const int g  = l >> 4;
    const int lg = l & 15;
    const int sg = w * 4 + g;

    float qx = P[0], qy = P[1], qz = P[2];
    __syncthreads();

    for (int k = 1; k < 512; ++k) {
        const float ddx = fmaxf(fmaxf(x0o - qx, qx - x1o), 0.0f);
        const float ddy = fmaxf(fmaxf(y0o - qy, qy - y1o), 0.0f);
        const float ddz = fmaxf(fmaxf(z0o - qz, qz - z1o), 0.0f);
        const float d2m = (ddx * ddx + ddy * ddy) + ddz * ddz;
        const float bm = __uint_as_float((unsigned)(bkeyS[t] >> 32));
        const bool act = (myCnt > 0) && (d2m <= bm * 1.0001f + 1e-9f);
        const unsigned long long pmask = __ballot(act);
        const int wcnt = __popcll(pmask);
        int wbase = 0;
        if (l == 0 && wcnt) wbase = atomicAdd(&qcntS, wcnt);
        wbase = __shfl(wbase, 0);
        if (act) curS[wbase + __popcll(pmask & ((1ull << l) - 1ull))] = t;
        __syncthreads();
        const int A = qcntS;

        for (int e = sg; e < A; e += 32) {
            const int bu = curS[e];
            const int base = offS[bu], cnt = cntS[bu];
            unsigned long long key = 0ull;
            int klane = l;
            float cx = 0.f, cy = 0.f, cz = 0.f;
            for (int c = lg; c < cnt; c += 16) {
                const float4 pt = SP[base + c];
                const float m = mind[base + c];
                const float d2 = sqd(pt.x, pt.y, pt.z, qx, qy, qz);
                const float nm = fminf(m, d2);
                mind[base + c] = nm;
                const unsigned long long kk = packkey(nm, __float_as_int(pt.w));
                if (kk > key) { key = kk; cx = pt.x; cy = pt.y; cz = pt.z; }
            }
#pragma unroll
            for (int s = 1; s < 16; s <<= 1) {
                const unsigned long long ok = __shfl_xor(key, s);
                const int ol2 = __shfl_xor(klane, s);
                if (ok > key) { key = ok; klane = ol2; }
            }
            const float wx = __shfl(cx, klane), wy = __shfl(cy, klane), wz = __shfl(cz, klane);
            if (lg == 0) {
                bkeyS[bu] = key;
                bxS[bu] = wx; byS[bu] = wy; bzS[bu] = wz;
            }
        }
        __syncthreads();

        unsigned long long key = bkeyS[t];
        int bu2 = t;
#pragma unroll
        for (int s = 1; s < 64; s <<= 1) {
            const unsigned long long ok = __shfl_xor(key, s);
            const int ob = __shfl_xor(bu2, s);
            if (ok > key) { key = ok; bu2 = ob; }
        }
        if (l == 0) { candK[w] = key; candB[w] = bu2; }
        if (t == 0) qcntS = 0;
        __syncthreads();
        unsigned long long wk = candK[0]; int wb = candB[0];
#pragma unroll
        for (int j = 1; j < 8; ++j) {
            const unsigned long long k2 = candK[j];
            if (k2 > wk) { wk = k2; wb = candB[j]; }
        }
        qx = bxS[wb]; qy = byS[wb]; qz = bzS[wb];
        if (t == 0) {
            gout[((size_t)b * 512 + k) * 3 + 0] = qx;
            gout[((size_t)b * 512 + k) * 3 + 1] = qy;
            gout[((size_t)b * 512 + k) * 3 + 2] = qz;
        }
    }
}

// ==================== mega kernel: entire post-FPS pipeline, 1 launch ====================

struct MegaArgs {
    const float *xyz;
    const float *s1w0, *s1b0, *s1w1, *s1b1, *s1w2, *s1b2;
    const float *s2w0, *s2b0, *s2w1, *s2b1;
    const float *s3w0, *s3b0, *s3w1, *s3b1;
    const float *s4w0, *s4b0, *s4w1, *s4b1;
    const float *p1w0, *p1b0, *p1w1, *p1b1;
    const float *p2w0, *p2b0, *p2w1, *p2b1;
    float *xyz1, *f1, *xyz2, *f2, *xyz3, *f3, *xyz4, *f4, *f5;
    int *nni1; float *nnw1; int *nni2; float *nnw2;
    float *bufA, *bufB;
    float *out;
};

// manual grid barrier:
//  - ONE release fence (L2 writeback) + relaxed RMW arrival;
//  - spin on a relaxed AGENT-scope atomic LOAD: serviced at the coherence point (sc1)
//    so remote-XCD arrivals are observed (no hang), with NO per-poll cache maintenance
//    (R10 bug: acquire-per-poll = L2 invalidate storm -> 28 GB FETCH) and NO RMW
//    serialization (R11 residual: 256 blocks' fetch_add spin saturated the atomic unit);
//  - ONE acquire fence (L2 invalidate) after the target is reached.
// All NBLK blocks co-resident (135KB LDS -> 1 block/CU, grid = CU count) -> no deadlock.
__device__ __forceinline__ void gridbar(int* bar, int phase) {
    __syncthreads();
    if (threadIdx.x == 0) {
        __builtin_amdgcn_fence(__ATOMIC_RELEASE, "agent");
        __hip_atomic_fetch_add(bar, 1, __ATOMIC_RELAXED, __HIP_MEMORY_SCOPE_AGENT);
        const int target = phase * NBLK;
        while (__hip_atomic_load(bar, __ATOMIC_RELAXED, __HIP_MEMORY_SCOPE_AGENT) < target) {
            __builtin_amdgcn_s_sleep(2);
        }
        __builtin_amdgcn_fence(__ATOMIC_ACQUIRE, "agent");
    }
    __syncthreads();
}

// ---- stage devices (numerics identical to R9/R10/R11) ----

template <int N, int NPOINT>
__device__ void fps_small_dev(const float* __restrict__ P, float* __restrict__ gout, int l) {
    constexpr int PPT = N / 64;
    float px[PPT], py[PPT], pz[PPT], md[PPT];
#pragma unroll
    for (int j = 0; j < PPT; ++j) {
        const int p = l + 64 * j;
        px[j] = P[p * 3]; py[j] = P[p * 3 + 1]; pz[j] = P[p * 3 + 2];
        md[j] = 1e30f;
    }
    float qx = P[0], qy = P[1], qz = P[2];
    if (l == 0) { gout[0] = qx; gout[1] = qy; gout[2] = qz; }
    for (int k = 1; k < NPOINT; ++k) {
        float bv = -1.0f;
        int   bi = 0;
#pragma unroll
        for (int j = 0; j < PPT; ++j) {
            md[j] = fminf(md[j], sqd(px[j], py[j], pz[j], qx, qy, qz));
            if (md[j] > bv) { bv = md[j]; bi = l + 64 * j; }
        }
#pragma unroll
        for (int off = 1; off < 64; off <<= 1) {
            float ov = __shfl_xor(bv, off);
            int   oi = __shfl_xor(bi, off);
            if (ov > bv || (ov == bv && oi < bi)) { bv = ov; bi = oi; }
        }
        const int ol = bi & 63, js = bi >> 6;
        float sx = px[0], sy = py[0], sz = pz[0];
#pragma unroll
        for (int j = 1; j < PPT; ++j) {
            if (j == js) { sx = px[j]; sy = py[j]; sz = pz[j]; }
        }
        qx = __shfl(sx, ol); qy = __shfl(sy, ol); qz = __shfl(sz, ol);
        if (l == 0) {
            gout[(size_t)k * 3 + 0] = qx;
            gout[(size_t)k * 3 + 1] = qy;
            gout[(size_t)k * 3 + 2] = qz;
        }
    }
}

__device__ void sa1_dev(const float* __restrict__ xyz, const float* __restrict__ centers,
                        const float* __restrict__ w0, const float* __restrict__ b0,
                        const float* __restrict__ w1, const float* __restrict__ b1,
                        const float* __restrict__ w2, const float* __restrict__ b2,
                        float* __restrict__ outf, float r2, float r,
                        int gc, int l, int* __restrict__ idxw, float (*__restrict__ hsw)[65]) {
    const int b = gc >> 9;
    const float* __restrict__ P = xyz + (size_t)b * 32768 * 3;
    const float* cp = centers + (size_t)gc * 3;
    const float cx = cp[0], cy = cp[1], cz = cp[2];
    const float sa_ = sum3sq(cx, cy, cz);

    int cnt = 0, first = -1;
    float nx = P[l * 3], ny = P[l * 3 + 1], nz = P[l * 3 + 2];
    for (int i0 = 0; i0 < 32768; i0 += 64) {
        const float bx = nx, by = ny, bz = nz;
        if (i0 + 64 < 32768) {
            const int ip = (i0 + 64 + l) * 3;
            nx = P[ip]; ny = P[ip + 1]; nz = P[ip + 2];
        }
        const float d2 = sqd_dot(cx, cy, cz, sa_, bx, by, bz);
        const bool in = d2 < r2;
        const unsigned long long mask = __ballot(in);
        if (first < 0 && mask != 0ull) first = i0 + __builtin_ctzll(mask);
        const int pos = cnt + __popcll(mask & ((1ull << l) - 1ull));
        if (in && pos < 64) idxw[pos] = i0 + l;
        cnt += __popcll(mask);
        if (cnt >= 64) break;
    }
    if (first < 0) first = 0;
    for (int p2 = cnt + l; p2 < 64; p2 += 64) idxw[p2] = first;

    const int n = idxw[l];
    const float* pp = P + (size_t)n * 3;
    float gi[3];
    gi[0] = (pp[0] - cx) / r; gi[1] = (pp[1] - cy) / r; gi[2] = (pp[2] - cz) / r;
    float h1[32];
#pragma unroll
    for (int o = 0; o < 32; ++o) {
        float acc = b0[o];
#pragma unroll
        for (int k = 0; k < 3; ++k) acc += gi[k] * w0[k * 32 + o];
        h1[o] = fmaxf(acc, 0.f);
    }
    float h2[32];
#pragma unroll
    for (int o = 0; o < 32; ++o) {
        float acc = b1[o];
#pragma unroll
        for (int k = 0; k < 32; ++k) acc += h1[k] * w1[k * 32 + o];
        h2[o] = fmaxf(acc, 0.f);
    }
#pragma unroll
    for (int o = 0; o < 64; ++o) {
        float acc = b2[o];
#pragma unroll
        for (int k = 0; k < 32; ++k) acc += h2[k] * w2[k * 64 + o];
        hsw[l][o] = fmaxf(acc, 0.f);
    }
    __threadfence_block();
    float mx = hsw[0][l];
    for (int s2 = 1; s2 < 64; ++s2) mx = fmaxf(mx, hsw[s2][l]);
    outf[(size_t)gc * 64 + l] = mx;
}

template <int NS>
__device__ void bqb_dev(const float* __restrict__ xyz_src, const float* __restrict__ centers,
                        const float* __restrict__ feats, float* __restrict__ g,
                        int N, int M, int CF, float r, float r2,
                        int wv, int l, int* __restrict__ idxw) {
    const int b = wv / M;
    const float* cp = centers + (size_t)wv * 3;
    const float ax = cp[0], ay = cp[1], az = cp[2];
    const float sa_ = sum3sq(ax, ay, az);
    const float* __restrict__ P = xyz_src + (size_t)b * N * 3;

    int cnt = 0, first = -1;
    float nx = P[l * 3], ny = P[l * 3 + 1], nz = P[l * 3 + 2];
    for (int i0 = 0; i0 < N; i0 += 64) {
        const float bx = nx, by = ny, bz = nz;
        if (i0 + 64 < N) {
            const int ip = (i0 + 64 + l) * 3;
            nx = P[ip]; ny = P[ip + 1]; nz = P[ip + 2];
        }
        const float d2 = sqd_dot(ax, ay, az, sa_, bx, by, bz);
        const bool in = d2 < r2;
        const unsigned long long mask = __ballot(in);
        if (first < 0 && mask != 0ull) first = i0 + __builtin_ctzll(mask);
        const int pos = cnt + __popcll(mask & ((1ull << l) - 1ull));
        if (in && pos < NS) idxw[pos] = i0 + l;
        cnt += __popcll(mask);
        if (cnt >= NS) break;
    }
    if (first < 0) first = 0;
    for (int p2 = cnt + l; p2 < NS; p2 += 64) idxw[p2] = first;

    for (int s = 0; s < NS; ++s) {
        const int n = idxw[s];
        float* go = g + ((size_t)wv * NS + s) * (3 + CF);
        const float* pp = P + (size_t)n * 3;
        if (l < 3) go[l] = (pp[l] - cp[l]) / r;
        for (int c = l; c < CF; c += 64) go[3 + c] = feats[((size_t)b * N + n) * CF + c];
    }
}

template <int COL2>
__device__ void dense_relu_dev(const float* __restrict__ X, const float* __restrict__ Wm,
                               const float* __restrict__ bias, float* __restrict__ Y,
                               int M, int CI, int gid) {
    const int CO = 1 << COL2;
    const int total = M << COL2;
    for (int i = gid; i < total; i += NTH) {
        const int m = i >> COL2, co = i & (CO - 1);
        const float* x = X + (size_t)m * CI;
        float acc = bias[co];
#pragma unroll 4
        for (int k = 0; k < CI; ++k) acc += x[k] * Wm[(size_t)k * CO + co];
        Y[(size_t)m * CO + co] = fmaxf(acc, 0.f);
    }
}

template <int COL2>
__device__ void dense_max_dev(const float* __restrict__ X, const float* __restrict__ Wm,
                              const float* __restrict__ bias, float* __restrict__ F,
                              int BM, int NS, int CI, int gid) {
    const int CO = 1 << COL2;
    const int total = BM << COL2;
    for (int i = gid; i < total; i += NTH) {
        const int bm = i >> COL2, co = i & (CO - 1);
        const float b0v = bias[co];
        float mx = -1e30f;
        for (int s = 0; s < NS; ++s) {
            const float* x = X + ((size_t)bm * NS + s) * CI;
            float acc = b0v;
#pragma unroll 4
            for (int k = 0; k < CI; ++k) acc += x[k] * Wm[(size_t)k * CO + co];
            mx = fmaxf(mx, fmaxf(acc, 0.f));
        }
        F[(size_t)bm * CO + co] = mx;
    }
}

__device__ void fp_nn_dev(const float* __restrict__ unk, const float* __restrict__ kn,
                          int* __restrict__ nni, float* __restrict__ nnw,
                          int NU, int NK, int t) {
    const int b = t / NU;
    const float* u = unk + (size_t)t * 3;
    const float ax = u[0], ay = u[1], az = u[2];
    const float sa_ = sum3sq(ax, ay, az);
    const float* K = kn + (size_t)b * NK * 3;
    float v0 = 1e30f, v1 = 1e30f, v2 = 1e30f;
    int   j0 = 0, j1 = 0, j2 = 0;
    for (int k = 0; k < NK; ++k) {
        const float d2 = sqd_dot(ax, ay, az, sa_, K[k * 3], K[k * 3 + 1], K[k * 3 + 2]);
        if (d2 < v0)      { v2 = v1; j2 = j1; v1 = v0; j1 = j0; v0 = d2; j0 = k; }
        else if (d2 < v1) { v2 = v1; j2 = j1; v1 = d2; j1 = k; }
        else if (d2 < v2) { v2 = d2; j2 = k; }
    }
    const float d0 = fmaxf(v0, 0.f), d1 = fmaxf(v1, 0.f), dd2 = fmaxf(v2, 0.f);
    float w0 = 1.f / (d0 + 1e-8f), w1 = 1.f / (d1 + 1e-8f), w2 = 1.f / (dd2 + 1e-8f);
    const float s = (w0 + w1) + w2;
    nnw[t * 3] = w0 / s; nnw[t * 3 + 1] = w1 / s; nnw[t * 3 + 2] = w2 / s;
    nni[t * 3] = j0; nni[t * 3 + 1] = j1; nni[t * 3 + 2] = j2;
}

template <int COL2>
__device__ void dense_fp_dev(const float* __restrict__ f1c, const float* __restrict__ f2c,
                             const int* __restrict__ nni, const float* __restrict__ nnw,
                             const float* __restrict__ Wm, const float* __restrict__ bias,
                             float* __restrict__ Y, int NU, int NK, int C1c, int C2c,
                             int gid) {
    const int CO = 1 << COL2;
    const int total = (4 * NU) << COL2;
    for (int i = gid; i < total; i += NTH) {
        const int m = i >> COL2, co = i & (CO - 1);
        const int b = m / NU;
        const int i0 = nni[m * 3], i1 = nni[m * 3 + 1], i2 = nni[m * 3 + 2];
        const float w0v = nnw[m * 3], w1v = nnw[m * 3 + 1], w2v = nnw[m * 3 + 2];
        const float* x1 = f1c + (size_t)m * C1c;
        const float* a  = f2c + ((size_t)b * NK + i0) * C2c;
        const float* bb = f2c + ((size_t)b * NK + i1) * C2c;
        const float* cc = f2c + ((size_t)b * NK + i2) * C2c;
        float acc = bias[co];
#pragma unroll 4
        for (int k = 0; k < C1c; ++k) acc += x1[k] * Wm[(size_t)k * CO + co];
#pragma unroll 4
        for (int k = 0; k < C2c; ++k) {
            const float xi = (w0v * a[k] + w1v * bb[k]) + w2v * cc[k];
            acc += xi * Wm[(size_t)(C1c + k) * CO + co];
        }
        Y[(size_t)m * CO + co] = fmaxf(acc, 0.f);
    }
}

__global__ __launch_bounds__(512) void mega(MegaArgs A, int* bar) {
    __shared__ float hsS[8][64][65];   // 133 KB -> 1 block/CU (guarantees co-residency)
    __shared__ int   idxS[8][64];
    const int tid = threadIdx.x;
    const int w = tid >> 6, l = tid & 63;
    const int gw = blockIdx.x * 8 + w;       // 0..2047
    const int gid = blockIdx.x * 512 + tid;  // 0..131071

    // T1: sa1 (2048 centers, wave per center)
    sa1_dev(A.xyz, A.xyz1, A.s1w0, A.s1b0, A.s1w1, A.s1b1, A.s1w2, A.s1b2,
            A.f1, 0.01f, 0.1f, gw, l, &idxS[w][0], &hsS[w][0]);
    gridbar(bar, 1);
    // T2: fps sa2
    if (gw < 4) fps_small_dev<512, 256>(A.xyz1 + (size_t)gw * 512 * 3,
                                        A.xyz2 + (size_t)gw * 256 * 3, l);
    gridbar(bar, 2);
    // T3: bq+build sa2 (1024 centers)
    if (gw < 1024) bqb_dev<32>(A.xyz1, A.xyz2, A.f1, A.bufA, 512, 256, 64,
                               0.2f, 0.04f, gw, l, &idxS[w][0]);
    gridbar(bar, 3);
    // T4: dense sa2 L0 (32768 x 67 -> 64)
    dense_relu_dev<6>(A.bufA, A.s2w0, A.s2b0, A.bufB, 32768, 67, gid);
    gridbar(bar, 4);
    // T5: dense+max sa2 L1 -> f2
    dense_max_dev<7>(A.bufB, A.s2w1, A.s2b1, A.f2, 1024, 32, 64, gid);
    gridbar(bar, 5);
    // T6: fps sa3
    if (gw < 4) fps_small_dev<256, 64>(A.xyz2 + (size_t)gw * 256 * 3,
                                       A.xyz3 + (size_t)gw * 64 * 3, l);
    gridbar(bar, 6);
    // T7: bq+build sa3 (256 centers)
    if (gw < 256) bqb_dev<16>(A.xyz2, A.xyz3, A.f2, A.bufA, 256, 64, 128,
                              0.4f, 0.16f, gw, l, &idxS[w][0]);
    gridbar(bar, 7);
    // T8: dense sa3 L0 (4096 x 131 -> 128)
    dense_relu_dev<7>(A.bufA, A.s3w0, A.s3b0, A.bufB, 4096, 131, gid);
    gridbar(bar, 8);
    // T9: dense+max sa3 -> f3
    dense_max_dev<8>(A.bufB, A.s3w1, A.s3b1, A.f3, 256, 16, 128, gid);
    gridbar(bar, 9);
    // T10: fps sa4
    if (gw < 4) fps_small_dev<64, 16>(A.xyz3 + (size_t)gw * 64 * 3,
                                      A.xyz4 + (size_t)gw * 16 * 3, l);
    gridbar(bar, 10);
    // T11: bq+build sa4 (64 centers)
    if (gw < 64) bqb_dev<16>(A.xyz3, A.xyz4, A.f3, A.bufA, 64, 16, 256,
                             0.8f, 0.64f, gw, l, &idxS[w][0]);
    gridbar(bar, 11);
    // T12: dense sa4 L0 (1024 x 259 -> 256)
    dense_relu_dev<8>(A.bufA, A.s4w0, A.s4b0, A.bufB, 1024, 259, gid);
    gridbar(bar, 12);
    // T13: dense+max sa4 -> f4  ||  fp_nn1, fp_nn2 on idle threads
    dense_max_dev<8>(A.bufB, A.s4w1, A.s4b1, A.f4, 64, 16, 256, gid);
    if (gid >= 16384 && gid < 16640) fp_nn_dev(A.xyz3, A.xyz4, A.nni1, A.nnw1, 64, 16, gid - 16384);
    else if (gid >= 16640 && gid < 17664) fp_nn_dev(A.xyz2, A.xyz3, A.nni2, A.nnw2, 256, 64, gid - 16640);
    gridbar(bar, 13);
    // T14: fp1 dense L0 (interp fused) -> bufA
    dense_fp_dev<8>(A.f3, A.f4, A.nni1, A.nnw1, A.p1w0, A.p1b0, A.bufA, 64, 16, 256, 256, gid);
    gridbar(bar, 14);
    // T15: fp1 dense L1 -> f5
    dense_relu_dev<7>(A.bufA, A.p1w1, A.p1b1, A.f5, 256, 256, gid);
    gridbar(bar, 15);
    // T16: fp2 dense L0 (interp fused) -> bufB
    dense_fp_dev<7>(A.f2, A.f5, A.nni2, A.nnw2, A.p2w0, A.p2b0, A.bufB, 256, 64, 128, 128, gid);
    gridbar(bar, 16);
    // T17: fp2 dense L1 -> out  +  copy xyz2 -> out tail
    dense_relu_dev<6>(A.bufB, A.p2w1, A.p2b1, A.out, 1024, 128, gid);
    for (int i = gid; i < 3072; i += NTH) A.out[65536 + i] = A.xyz2[i];
}

// ---------------- host launcher ----------------

extern "C" void kernel_launch(void* const* d_in, const int* in_sizes, int n_in,
                              void* d_out, int out_size, void* d_ws, size_t ws_size,
                              hipStream_t stream) {
    float* W = (float*)d_ws;
    size_t off = 0;
    auto A_ = [&](size_t n) { size_t o = off; off += (n + 63) & ~(size_t)63; return o; };
    const size_t o_xyz1 = A_(4 * 512 * 3);
    const size_t o_f1   = A_(4 * 512 * 64);
    const size_t o_xyz2 = A_(4 * 256 * 3);
    const size_t o_f2   = A_(4 * 256 * 128);
    const size_t o_xyz3 = A_(4 * 64 * 3);
    const size_t o_f3   = A_(4 * 64 * 256);
    const size_t o_xyz4 = A_(4 * 16 * 3);
    const size_t o_f4   = A_(4 * 16 * 256);
    const size_t o_f5   = A_(4 * 64 * 128);
    const size_t o_nni1 = A_(4 * 64 * 3);
    const size_t o_nnw1 = A_(4 * 64 * 3);
    const size_t o_nni2 = A_(4 * 256 * 3);
    const size_t o_nnw2 = A_(4 * 256 * 3);
    const size_t o_bar  = A_(64);
    const size_t o_sort = A_((size_t)4 * 32768 * 4);
    const size_t o_bufA = A_((size_t)32768 * 128);
    const size_t o_bufB = A_((size_t)32768 * 64);
    if (off * sizeof(float) > ws_size) return;

    MegaArgs M;
    M.xyz  = (const float*)d_in[0];
    M.s1w0 = (const float*)d_in[1];  M.s1b0 = (const float*)d_in[2];
    M.s1w1 = (const float*)d_in[3];  M.s1b1 = (const float*)d_in[4];
    M.s1w2 = (const float*)d_in[5];  M.s1b2 = (const float*)d_in[6];
    M.s2w0 = (const float*)d_in[7];  M.s2b0 = (const float*)d_in[8];
    M.s2w1 = (const float*)d_in[9];  M.s2b1 = (const float*)d_in[10];
    M.s3w0 = (const float*)d_in[11]; M.s3b0 = (const float*)d_in[12];
    M.s3w1 = (const float*)d_in[13]; M.s3b1 = (const float*)d_in[14];
    M.s4w0 = (const float*)d_in[15]; M.s4b0 = (const float*)d_in[16];
    M.s4w1 = (const float*)d_in[17]; M.s4b1 = (const float*)d_in[18];
    M.p1w0 = (const float*)d_in[19]; M.p1b0 = (const float*)d_in[20];
    M.p1w1 = (const float*)d_in[21]; M.p1b1 = (const float*)d_in[22];
    M.p2w0 = (const float*)d_in[23]; M.p2b0 = (const float*)d_in[24];
    M.p2w1 = (const float*)d_in[25]; M.p2b1 = (const float*)d_in[26];
    M.xyz1 = W + o_xyz1; M.f1 = W + o_f1;
    M.xyz2 = W + o_xyz2; M.f2 = W + o_f2;
    M.xyz3 = W + o_xyz3; M.f3 = W + o_f3;
    M.xyz4 = W + o_xyz4; M.f4 = W + o_f4;
    M.f5   = W + o_f5;
    M.nni1 = (int*)(W + o_nni1); M.nnw1 = W + o_nnw1;
    M.nni2 = (int*)(W + o_nni2); M.nnw2 = W + o_nnw2;
    M.bufA = W + o_bufA; M.bufB = W + o_bufB;
    M.out  = (float*)d_out;
    int* bar = (int*)(W + o_bar);
    float4* sortP = (float4*)(W + o_sort);

    hipMemsetAsync(bar, 0, sizeof(int), stream);
    fps_sub<<<4, 512, 0, stream>>>(M.xyz, sortP, M.xyz1);
    mega<<<NBLK, 512, 0, stream>>>(M, bar);
}

// Round 13
// 2206.378 us; speedup vs baseline: 1.1959x; 1.1959x over previous
//
#include <hip/hip_runtime.h>
#include <cstddef>

// ---------------- numerics helpers (mirror reference FP32 op order) ----------------

__device__ __forceinline__ float sqd(float x, float y, float z, float qx, float qy, float qz) {
#pragma clang fp contract(off)
    float dx = x - qx, dy = y - qy, dz = z - qz;
    return (dx * dx + dy * dy) + dz * dz;
}

__device__ __forceinline__ float sum3sq(float x, float y, float z) {
#pragma clang fp contract(off)
    return (x * x + y * y) + z * z;
}

// reference _sqdist: sum(a^2) + sum(b^2) - 2*dot(a,b)
__device__ __forceinline__ float sqd_dot(float ax, float ay, float az, float sa_,
                                         float bx, float by, float bz) {
#pragma clang fp contract(off)
    float sb = (bx * bx + by * by) + bz * bz;
    float dt = (ax * bx + ay * by) + az * bz;
    return (sa_ + sb) - 2.0f * dt;
}

// packed argmax key: (float bits of val << 32) | ~orig. mind >= 0 -> monotonic;
// max key == (val desc, orig asc) == reference first-occurrence argmax.
__device__ __forceinline__ unsigned long long packkey(float v, int orig) {
    return ((unsigned long long)__float_as_uint(v) << 32) | (unsigned)(~orig);
}

// ---------------- FPS large (N=32768, npoint=512): R6-proven bucket pruning ------------
// Writes gathered coords directly (xyz1 = selected points, in selection order).

__global__ __launch_bounds__(512) void fps_sub(const float* __restrict__ xyz,
                                               float4* __restrict__ SPall,
                                               float* __restrict__ gout) {
    const int b = blockIdx.x, t = threadIdx.x, w = t >> 6, l = t & 63;
    const float* __restrict__ P = xyz + (size_t)b * 32768 * 3;
    float4* __restrict__ SP = SPall + (size_t)b * 32768;

    __shared__ float mind[32768];
    __shared__ int   cntS[512], offS[512], curS[512];
    __shared__ unsigned long long bkeyS[512];
    __shared__ float bxS[512], byS[512], bzS[512];
    __shared__ unsigned long long candK[8];
    __shared__ int   candB[8];
    __shared__ float bbS[6];
    __shared__ float scr[48];
    __shared__ int   qcntS;

    float mnx = 1e30f, mny = 1e30f, mnz = 1e30f;
    float mxx = -1e30f, mxy = -1e30f, mxz = -1e30f;
    for (int p = t; p < 32768; p += 512) {
        const float x = P[3 * p], y = P[3 * p + 1], z = P[3 * p + 2];
        mnx = fminf(mnx, x); mxx = fmaxf(mxx, x);
        mny = fminf(mny, y); mxy = fmaxf(mxy, y);
        mnz = fminf(mnz, z); mxz = fmaxf(mxz, z);
    }
#pragma unroll
    for (int o = 1; o < 64; o <<= 1) {
        mnx = fminf(mnx, __shfl_xor(mnx, o)); mxx = fmaxf(mxx, __shfl_xor(mxx, o));
        mny = fminf(mny, __shfl_xor(mny, o)); mxy = fmaxf(mxy, __shfl_xor(mxy, o));
        mnz = fminf(mnz, __shfl_xor(mnz, o)); mxz = fmaxf(mxz, __shfl_xor(mxz, o));
    }
    if (l == 0) {
        scr[w] = mnx; scr[8 + w] = mny; scr[16 + w] = mnz;
        scr[24 + w] = mxx; scr[32 + w] = mxy; scr[40 + w] = mxz;
    }
    __syncthreads();
    if (t == 0) {
        float a0 = 1e30f, a1 = 1e30f, a2 = 1e30f, a3 = -1e30f, a4 = -1e30f, a5 = -1e30f;
        for (int i = 0; i < 8; ++i) {
            a0 = fminf(a0, scr[i]);      a1 = fminf(a1, scr[8 + i]);
            a2 = fminf(a2, scr[16 + i]); a3 = fmaxf(a3, scr[24 + i]);
            a4 = fmaxf(a4, scr[32 + i]); a5 = fmaxf(a5, scr[40 + i]);
        }
        bbS[0] = a0; bbS[1] = a1; bbS[2] = a2; bbS[3] = a3; bbS[4] = a4; bbS[5] = a5;
        qcntS = 0;
    }
    __syncthreads();
    const float bx0 = bbS[0], by0 = bbS[1], bz0 = bbS[2];
    const float ex = bbS[3] - bx0, ey = bbS[4] - by0, ez = bbS[5] - bz0;
    const float ivx = ex > 1e-20f ? 8.0f / ex : 0.0f;
    const float ivy = ey > 1e-20f ? 8.0f / ey : 0.0f;
    const float ivz = ez > 1e-20f ? 8.0f / ez : 0.0f;

    cntS[t] = 0;
    __syncthreads();
    for (int p = t; p < 32768; p += 512) {
        const float x = P[3 * p], y = P[3 * p + 1], z = P[3 * p + 2];
        const int ix = min(7, (int)((x - bx0) * ivx));
        const int iy = min(7, (int)((y - by0) * ivy));
        const int iz = min(7, (int)((z - bz0) * ivz));
        atomicAdd(&cntS[(iz * 8 + iy) * 8 + ix], 1);
    }
    __syncthreads();

    offS[t] = cntS[t];
    __syncthreads();
    for (int d = 1; d < 512; d <<= 1) {
        const int v = (t >= d) ? offS[t - d] : 0;
        __syncthreads();
        offS[t] += v;
        __syncthreads();
    }
    const int myexc = offS[t] - cntS[t];
    offS[t] = myexc;
    curS[t] = myexc;
    __syncthreads();

    for (int p = t; p < 32768; p += 512) {
        const float x = P[3 * p], y = P[3 * p + 1], z = P[3 * p + 2];
        const int ix = min(7, (int)((x - bx0) * ivx));
        const int iy = min(7, (int)((y - by0) * ivy));
        const int iz = min(7, (int)((z - bz0) * ivz));
        const int pos = atomicAdd(&curS[(iz * 8 + iy) * 8 + ix], 1);
        SP[pos] = make_float4(x, y, z, __int_as_float(p));
    }
    for (int s = t; s < 32768; s += 512) mind[s] = 1e30f;
    const int myCnt = cntS[t];
    bkeyS[t] = (myCnt > 0) ? packkey(1e30f, 0x7fffffff) : 0ull;
    bxS[t] = 0.f; byS[t] = 0.f; bzS[t] = 0.f;
    if (t == 0) {
        gout[(size_t)b * 512 * 3 + 0] = P[0];
        gout[(size_t)b * 512 * 3 + 1] = P[1];
        gout[(size_t)b * 512 * 3 + 2] = P[2];
    }

    const int oix = t & 7, oiy = (t >> 3) & 7, oiz = t >> 6;
    const float gwx = ex * 0.125f, gwy = ey * 0.125f, gwz = ez * 0.125f;
    const float x0o = bx0 + oix * gwx, x1o = x0o + gwx;
    const float y0o = by0 + oiy * gwy, y1o = y0o + gwy;
    const float z0o = bz0 + oiz * gwz, z1o = z0o + gwz;

    const int g  = l >> 4;
    const int lg = l & 15;
    const int sg = w * 4 + g;

    float qx = P[0], qy = P[1], qz = P[2];
    __syncthreads();

    for (int k = 1; k < 512; ++k) {
        const float ddx = fmaxf(fmaxf(x0o - qx, qx - x1o), 0.0f);
        const float ddy = fmaxf(fmaxf(y0o - qy, qy - y1o), 0.0f);
        const float ddz = fmaxf(fmaxf(z0o - qz, qz - z1o), 0.0f);
        const float d2m = (ddx * ddx + ddy * ddy) + ddz * ddz;
        const float bm = __uint_as_float((unsigned)(bkeyS[t] >> 32));
        const bool act = (myCnt > 0) && (d2m <= bm * 1.0001f + 1e-9f);
        const unsigned long long pmask = __ballot(act);
        const int wcnt = __popcll(pmask);
        int wbase = 0;
        if (l == 0 && wcnt) wbase = atomicAdd(&qcntS, wcnt);
        wbase = __shfl(wbase, 0);
        if (act) curS[wbase + __popcll(pmask & ((1ull << l) - 1ull))] = t;
        __syncthreads();
        const int A = qcntS;

        for (int e = sg; e < A; e += 32) {
            const int bu = curS[e];
            const int base = offS[bu], cnt = cntS[bu];
            unsigned long long key = 0ull;
            int klane = l;
            float cx = 0.f, cy = 0.f, cz = 0.f;
            for (int c = lg; c < cnt; c += 16) {
                const float4 pt = SP[base + c];
                const float m = mind[base + c];
                const float d2 = sqd(pt.x, pt.y, pt.z, qx, qy, qz);
                const float nm = fminf(m, d2);
                mind[base + c] = nm;
                const unsigned long long kk = packkey(nm, __float_as_int(pt.w));
                if (kk > key) { key = kk; cx = pt.x; cy = pt.y; cz = pt.z; }
            }
#pragma unroll
            for (int s = 1; s < 16; s <<= 1) {
                const unsigned long long ok = __shfl_xor(key, s);
                const int ol2 = __shfl_xor(klane, s);
                if (ok > key) { key = ok; klane = ol2; }
            }
            const float wx = __shfl(cx, klane), wy = __shfl(cy, klane), wz = __shfl(cz, klane);
            if (lg == 0) {
                bkeyS[bu] = key;
                bxS[bu] = wx; byS[bu] = wy; bzS[bu] = wz;
            }
        }
        __syncthreads();

        unsigned long long key = bkeyS[t];
        int bu2 = t;
#pragma unroll
        for (int s = 1; s < 64; s <<= 1) {
            const unsigned long long ok = __shfl_xor(key, s);
            const int ob = __shfl_xor(bu2, s);
            if (ok > key) { key = ok; bu2 = ob; }
        }
        if (l == 0) { candK[w] = key; candB[w] = bu2; }
        if (t == 0) qcntS = 0;
        __syncthreads();
        unsigned long long wk = candK[0]; int wb = candB[0];
#pragma unroll
        for (int j = 1; j < 8; ++j) {
            const unsigned long long k2 = candK[j];
            if (k2 > wk) { wk = k2; wb = candB[j]; }
        }
        qx = bxS[wb]; qy = byS[wb]; qz = bzS[wb];
        if (t == 0) {
            gout[((size_t)b * 512 + k) * 3 + 0] = qx;
            gout[((size_t)b * 512 + k) * 3 + 1] = qy;
            gout[((size_t)b * 512 + k) * 3 + 2] = qz;
        }
    }
}

// ---------------- FPS, small (N<=512), one wave per batch; writes gathered coords ------

template <int N, int NPOINT>
__global__ __launch_bounds__(64) void fps_small(const float* __restrict__ pts,
                                                float* __restrict__ gout) {
    constexpr int PPT = N / 64;
    const int b = blockIdx.x, l = threadIdx.x;
    const float* __restrict__ P = pts + (size_t)b * N * 3;
    float px[PPT], py[PPT], pz[PPT], md[PPT];
#pragma unroll
    for (int j = 0; j < PPT; ++j) {
        const int p = l + 64 * j;
        px[j] = P[p * 3]; py[j] = P[p * 3 + 1]; pz[j] = P[p * 3 + 2];
        md[j] = 1e30f;
    }
    float qx = P[0], qy = P[1], qz = P[2];
    if (l == 0) {
        gout[(size_t)b * NPOINT * 3 + 0] = qx;
        gout[(size_t)b * NPOINT * 3 + 1] = qy;
        gout[(size_t)b * NPOINT * 3 + 2] = qz;
    }
    for (int k = 1; k < NPOINT; ++k) {
        float bv = -1.0f;
        int   bi = 0;
#pragma unroll
        for (int j = 0; j < PPT; ++j) {
            md[j] = fminf(md[j], sqd(px[j], py[j], pz[j], qx, qy, qz));
            if (md[j] > bv) { bv = md[j]; bi = l + 64 * j; }
        }
#pragma unroll
        for (int off = 1; off < 64; off <<= 1) {
            float ov = __shfl_xor(bv, off);
            int   oi = __shfl_xor(bi, off);
            if (ov > bv || (ov == bv && oi < bi)) { bv = ov; bi = oi; }
        }
        const int ol = bi & 63, js = bi >> 6;
        float sx = px[0], sy = py[0], sz = pz[0];
#pragma unroll
        for (int j = 1; j < PPT; ++j) {
            if (j == js) { sx = px[j]; sy = py[j]; sz = pz[j]; }
        }
        qx = __shfl(sx, ol); qy = __shfl(sy, ol); qz = __shfl(sz, ol);
        if (l == 0) {
            gout[((size_t)b * NPOINT + k) * 3 + 0] = qx;
            gout[((size_t)b * NPOINT + k) * 3 + 1] = qy;
            gout[((size_t)b * NPOINT + k) * 3 + 2] = qz;
        }
    }
}

// ---------------- ball query: first NS points with d2 < r2, pad with first hit ---------

template <int NS>
__global__ __launch_bounds__(256) void ball_query_k(const float* __restrict__ xyz,
                                                    const float* __restrict__ centers,
                                                    int* __restrict__ out,
                                                    int N, int M, float r2) {
    const int wv = blockIdx.x * 4 + (threadIdx.x >> 6);
    const int l  = threadIdx.x & 63;
    const int b  = wv / M;
    const float* cp = centers + (size_t)wv * 3;
    const float ax = cp[0], ay = cp[1], az = cp[2];
    const float sa_ = sum3sq(ax, ay, az);
    const float* __restrict__ P = xyz + (size_t)b * N * 3;
    int* o = out + (size_t)wv * NS;

    int cnt = 0, first = -1;
    float nx = P[l * 3], ny = P[l * 3 + 1], nz = P[l * 3 + 2];
    for (int i0 = 0; i0 < N; i0 += 64) {
        const float bx = nx, by = ny, bz = nz;
        if (i0 + 64 < N) {
            const int ip = (i0 + 64 + l) * 3;
            nx = P[ip]; ny = P[ip + 1]; nz = P[ip + 2];
        }
        const float d2 = sqd_dot(ax, ay, az, sa_, bx, by, bz);
        const bool in = d2 < r2;
        const unsigned long long mask = __ballot(in);
        if (first < 0 && mask != 0ull) first = i0 + __builtin_ctzll(mask);
        const int pos = cnt + __popcll(mask & ((1ull << l) - 1ull));
        if (in && pos < NS) o[pos] = i0 + l;
        cnt += __popcll(mask);
        if (cnt >= NS) break;
    }
    if (first < 0) first = 0;
    for (int p2 = cnt + l; p2 < NS; p2 += 64) o[p2] = first;
}

// ---------------- fused SA for sa1: gather + normalize + 3-layer MLP + max ----------------

template <int NS, int CF, int C1, int C2, int C3>
__global__ __launch_bounds__(64) void sa_fused(
    const float* __restrict__ xyz, const float* __restrict__ feats,
    const float* __restrict__ centers, const int* __restrict__ idx,
    const float* __restrict__ w0, const float* __restrict__ b0,
    const float* __restrict__ w1, const float* __restrict__ b1,
    const float* __restrict__ w2, const float* __restrict__ b2,
    float* __restrict__ outf, int N, int M, float r) {
    constexpr int CIN = 3 + CF;
    constexpr int CL  = (C3 > 0) ? C3 : C2;
    constexpr int CPB = 64 / NS;
    const int tid = threadIdx.x;
    const int ci = tid / NS, s = tid % NS;
    const int gc = blockIdx.x * CPB + ci;
    const int b  = gc / M;
    const float* cp = centers + (size_t)gc * 3;
    const float cx = cp[0], cy = cp[1], cz = cp[2];
    const int n = idx[(size_t)gc * NS + s];
    const float* pp = xyz + ((size_t)b * N + n) * 3;
    float gi[CIN];
    gi[0] = (pp[0] - cx) / r; gi[1] = (pp[1] - cy) / r; gi[2] = (pp[2] - cz) / r;
    if constexpr (CF > 0) {
        const float* fr = feats + ((size_t)b * N + n) * CF;
#pragma unroll
        for (int c = 0; c < CF; ++c) gi[3 + c] = fr[c];
    }
    float h1[C1];
#pragma unroll
    for (int o = 0; o < C1; ++o) {
        float acc = b0[o];
#pragma unroll
        for (int k = 0; k < CIN; ++k) acc += gi[k] * w0[k * C1 + o];
        h1[o] = fmaxf(acc, 0.f);
    }
    float h2[C2];
#pragma unroll
    for (int o = 0; o < C2; ++o) {
        float acc = b1[o];
#pragma unroll
        for (int k = 0; k < C1; ++k) acc += h1[k] * w1[k * C2 + o];
        h2[o] = fmaxf(acc, 0.f);
    }
    float hl[CL];
    if constexpr (C3 > 0) {
#pragma unroll
        for (int o = 0; o < C3; ++o) {
            float acc = b2[o];
#pragma unroll
            for (int k = 0; k < C2; ++k) acc += h2[k] * w2[k * C3 + o];
            hl[o] = fmaxf(acc, 0.f);
        }
    } else {
#pragma unroll
        for (int o = 0; o < CL; ++o) hl[o] = h2[o];
    }
    __shared__ float hs[64][CL + 1];
#pragma unroll
    for (int c = 0; c < CL; ++c) hs[tid][c] = hl[c];
    __syncthreads();
    for (int cc = 0; cc < CPB; ++cc) {
        for (int c = tid; c < CL; c += 64) {
            float mx = hs[cc * NS][c];
            for (int s2 = 1; s2 < NS; ++s2) mx = fmaxf(mx, hs[cc * NS + s2][c]);
            outf[(size_t)(blockIdx.x * CPB + cc) * CL + c] = mx;
        }
    }
}

// ---------------- build grouped input rows: [(p-c)/r | feats[n]] ----------------

__global__ void build_g(const float* __restrict__ xyz, const float* __restrict__ feats,
                        const float* __restrict__ centers, const int* __restrict__ idx,
                        float* __restrict__ g, int N, int M, int NS, int CF, float r) {
    const int row = blockIdx.x * 4 + (threadIdx.x >> 6);
    const int l   = threadIdx.x & 63;
    const int gc  = row / NS;
    const int b   = gc / M;
    const int n   = idx[row];
    const float* cp = centers + (size_t)gc * 3;
    const float* pp = xyz + ((size_t)b * N + n) * 3;
    float* go = g + (size_t)row * (3 + CF);
    if (l < 3) go[l] = (pp[l] - cp[l]) / r;
    for (int c = l; c < CF; c += 64) go[3 + c] = feats[((size_t)b * N + n) * CF + c];
}

// ---------------- dense layer + relu ----------------

__global__ void dense_relu(const float* __restrict__ X, const float* __restrict__ Wm,
                           const float* __restrict__ bias, float* __restrict__ Y,
                           int M, int CI, int CO) {
    const int co = blockIdx.x * 64 + threadIdx.x;
    const int m  = blockIdx.y * 4 + threadIdx.y;
    const float* x = X + (size_t)m * CI;
    float acc = bias[co];
#pragma unroll 4
    for (int k = 0; k < CI; ++k) acc += x[k] * Wm[(size_t)k * CO + co];
    Y[(size_t)m * CO + co] = fmaxf(acc, 0.f);
}

// ---------------- max over samples ----------------

__global__ void max_ns(const float* __restrict__ H, float* __restrict__ F,
                       int BM, int NS, int C) {
    const int tid = blockIdx.x * 256 + threadIdx.x;
    if (tid >= BM * C) return;
    const int bm = tid / C, c = tid % C;
    const float* h = H + ((size_t)bm * NS) * C + c;
    float mx = h[0];
    for (int s = 1; s < NS; ++s) mx = fmaxf(mx, h[(size_t)s * C]);
    F[tid] = mx;
}

// ---------------- FP: 3-NN + inverse-distance weights ----------------

__global__ void fp_nn(const float* __restrict__ unk, const float* __restrict__ kn,
                      int* __restrict__ nni, float* __restrict__ nnw, int NU, int NK) {
    const int t = blockIdx.x * blockDim.x + threadIdx.x;
    const int b = t / NU;
    const float* u = unk + (size_t)t * 3;
    const float ax = u[0], ay = u[1], az = u[2];
    const float sa_ = sum3sq(ax, ay, az);
    const float* K = kn + (size_t)b * NK * 3;
    float v0 = 1e30f, v1 = 1e30f, v2 = 1e30f;
    int   j0 = 0, j1 = 0, j2 = 0;
    for (int k = 0; k < NK; ++k) {
        const float d2 = sqd_dot(ax, ay, az, sa_, K[k * 3], K[k * 3 + 1], K[k * 3 + 2]);
        if (d2 < v0)      { v2 = v1; j2 = j1; v1 = v0; j1 = j0; v0 = d2; j0 = k; }
        else if (d2 < v1) { v2 = v1; j2 = j1; v1 = d2; j1 = k; }
        else if (d2 < v2) { v2 = d2; j2 = k; }
    }
    const float d0 = fmaxf(v0, 0.f), d1 = fmaxf(v1, 0.f), dd2 = fmaxf(v2, 0.f);
    float w0 = 1.f / (d0 + 1e-8f), w1 = 1.f / (d1 + 1e-8f), w2 = 1.f / (dd2 + 1e-8f);
    const float s = (w0 + w1) + w2;
    nnw[t * 3] = w0 / s; nnw[t * 3 + 1] = w1 / s; nnw[t * 3 + 2] = w2 / s;
    nni[t * 3] = j0; nni[t * 3 + 1] = j1; nni[t * 3 + 2] = j2;
}

// ---------------- FP: concat [feats1 | interp(feats2)] ----------------

__global__ void interp_concat(const float* __restrict__ f1, const float* __restrict__ f2,
                              const int* __restrict__ nni, const float* __restrict__ nnw,
                              float* __restrict__ X, int NU, int NK, int C1c, int C2c) {
    const int row = blockIdx.x * 4 + (threadIdx.x >> 6);
    const int l   = threadIdx.x & 63;
    const int b   = row / NU;
    const int i0 = nni[row * 3], i1 = nni[row * 3 + 1], i2 = nni[row * 3 + 2];
    const float w0 = nnw[row * 3], w1 = nnw[row * 3 + 1], w2 = nnw[row * 3 + 2];
    float* xo = X + (size_t)row * (C1c + C2c);
    for (int c = l; c < C1c; c += 64) xo[c] = f1[(size_t)row * C1c + c];
    const float* a  = f2 + ((size_t)b * NK + i0) * C2c;
    const float* bb = f2 + ((size_t)b * NK + i1) * C2c;
    const float* cc = f2 + ((size_t)b * NK + i2) * C2c;
    for (int c = l; c < C2c; c += 64) xo[C1c + c] = (w0 * a[c] + w1 * bb[c]) + w2 * cc[c];
}

__global__ void copyf(const float* __restrict__ src, float* __restrict__ dst, int n) {
    const int i = blockIdx.x * 256 + threadIdx.x;
    if (i < n) dst[i] = src[i];
}

// ---------------- host launcher ----------------

extern "C" void kernel_launch(void* const* d_in, const int* in_sizes, int n_in,
                              void* d_out, int out_size, void* d_ws, size_t ws_size,
                              hipStream_t stream) {
    const float* xyz  = (const float*)d_in[0];
    const float* s1w0 = (const float*)d_in[1],  *s1b0 = (const float*)d_in[2];
    const float* s1w1 = (const float*)d_in[3],  *s1b1 = (const float*)d_in[4];
    const float* s1w2 = (const float*)d_in[5],  *s1b2 = (const float*)d_in[6];
    const float* s2w0 = (const float*)d_in[7],  *s2b0 = (const float*)d_in[8];
    const float* s2w1 = (const float*)d_in[9],  *s2b1 = (const float*)d_in[10];
    const float* s3w0 = (const float*)d_in[11], *s3b0 = (const float*)d_in[12];
    const float* s3w1 = (const float*)d_in[13], *s3b1 = (const float*)d_in[14];
    const float* s4w0 = (const float*)d_in[15], *s4b0 = (const float*)d_in[16];
    const float* s4w1 = (const float*)d_in[17], *s4b1 = (const float*)d_in[18];
    const float* p1w0 = (const float*)d_in[19], *p1b0 = (const float*)d_in[20];
    const float* p1w1 = (const float*)d_in[21], *p1b1 = (const float*)d_in[22];
    const float* p2w0 = (const float*)d_in[23], *p2b0 = (const float*)d_in[24];
    const float* p2w1 = (const float*)d_in[25], *p2b1 = (const float*)d_in[26];
    float* out = (float*)d_out;
    float* W = (float*)d_ws;

    size_t off = 0;
    auto A_ = [&](size_t n) { size_t o = off; off += (n + 63) & ~(size_t)63; return o; };
    const size_t o_xyz1  = A_(4 * 512 * 3);
    const size_t o_idx1  = A_(4 * 512 * 64);
    const size_t o_f1    = A_(4 * 512 * 64);
    const size_t o_xyz2  = A_(4 * 256 * 3);
    const size_t o_idx2  = A_(4 * 256 * 32);
    const size_t o_f2    = A_(4 * 256 * 128);
    const size_t o_xyz3  = A_(4 * 64 * 3);
    const size_t o_idx3  = A_(4 * 64 * 16);
    const size_t o_f3    = A_(4 * 64 * 256);
    const size_t o_xyz4  = A_(4 * 16 * 3);
    const size_t o_idx4  = A_(4 * 16 * 16);
    const size_t o_f4    = A_(4 * 16 * 256);
    const size_t o_f5    = A_(4 * 64 * 128);
    const size_t o_nni1  = A_(4 * 64 * 3);
    const size_t o_nnw1  = A_(4 * 64 * 3);
    const size_t o_nni2  = A_(4 * 256 * 3);
    const size_t o_nnw2  = A_(4 * 256 * 3);
    const size_t o_sort  = A_((size_t)4 * 32768 * 4);  // float4 sorted points
    const size_t o_bufA  = A_((size_t)32768 * 128);    // 16 MiB arena
    const size_t o_bufB  = A_((size_t)32768 * 64);     //  8 MiB arena
    if (off * sizeof(float) > ws_size) return;  // fail loudly (validation will catch)

    float* xyz1  = W + o_xyz1;
    int*   idx1  = (int*)(W + o_idx1);  float* f1   = W + o_f1;
    float* xyz2  = W + o_xyz2;
    int*   idx2  = (int*)(W + o_idx2);  float* f2   = W + o_f2;
    float* xyz3  = W + o_xyz3;
    int*   idx3  = (int*)(W + o_idx3);  float* f3   = W + o_f3;
    float* xyz4  = W + o_xyz4;
    int*   idx4  = (int*)(W + o_idx4);  float* f4   = W + o_f4;
    float* f5    = W + o_f5;
    int*   nni1  = (int*)(W + o_nni1);  float* nnw1 = W + o_nnw1;
    int*   nni2  = (int*)(W + o_nni2);  float* nnw2 = W + o_nnw2;
    float4* sortP = (float4*)(W + o_sort);
    float* bufA  = W + o_bufA;
    float* bufB  = W + o_bufB;

    // -------- sa1: npoint=512, r=0.1, ns=64, MLP 3->32->32->64 --------
    fps_sub<<<4, 512, 0, stream>>>(xyz, sortP, xyz1);
    ball_query_k<64><<<512, 256, 0, stream>>>(xyz, xyz1, idx1, 32768, 512, (float)(0.1 * 0.1));
    sa_fused<64, 0, 32, 32, 64><<<2048, 64, 0, stream>>>(
        xyz, nullptr, xyz1, idx1, s1w0, s1b0, s1w1, s1b1, s1w2, s1b2, f1, 32768, 512, 0.1f);

    // -------- sa2: npoint=256, r=0.2, ns=32, MLP 67->64->128 --------
    fps_small<512, 256><<<4, 64, 0, stream>>>(xyz1, xyz2);
    ball_query_k<32><<<256, 256, 0, stream>>>(xyz1, xyz2, idx2, 512, 256, (float)(0.2 * 0.2));
    build_g<<<32768 / 4, 256, 0, stream>>>(xyz1, f1, xyz2, idx2, bufA, 512, 256, 32, 64, 0.2f);
    dense_relu<<<dim3(1, 32768 / 4), dim3(64, 4), 0, stream>>>(bufA, s2w0, s2b0, bufB, 32768, 67, 64);
    dense_relu<<<dim3(2, 32768 / 4), dim3(64, 4), 0, stream>>>(bufB, s2w1, s2b1, bufA, 32768, 64, 128);
    max_ns<<<(1024 * 128 + 255) / 256, 256, 0, stream>>>(bufA, f2, 1024, 32, 128);

    // -------- sa3: npoint=64, r=0.4, ns=16, MLP 131->128->256 --------
    fps_small<256, 64><<<4, 64, 0, stream>>>(xyz2, xyz3);
    ball_query_k<16><<<64, 256, 0, stream>>>(xyz2, xyz3, idx3, 256, 64, (float)(0.4 * 0.4));
    build_g<<<4096 / 4, 256, 0, stream>>>(xyz2, f2, xyz3, idx3, bufA, 256, 64, 16, 128, 0.4f);
    dense_relu<<<dim3(2, 4096 / 4), dim3(64, 4), 0, stream>>>(bufA, s3w0, s3b0, bufB, 4096, 131, 128);
    dense_relu<<<dim3(4, 4096 / 4), dim3(64, 4), 0, stream>>>(bufB, s3w1, s3b1, bufA, 4096, 128, 256);
    max_ns<<<(256 * 256 + 255) / 256, 256, 0, stream>>>(bufA, f3, 256, 16, 256);

    // -------- sa4: npoint=16, r=0.8, ns=16, MLP 259->256->256 --------
    fps_small<64, 16><<<4, 64, 0, stream>>>(xyz3, xyz4);
    ball_query_k<16><<<16, 256, 0, stream>>>(xyz3, xyz4, idx4, 64, 16, (float)(0.8 * 0.8));
    build_g<<<1024 / 4, 256, 0, stream>>>(xyz3, f3, xyz4, idx4, bufA, 64, 16, 16, 256, 0.8f);
    dense_relu<<<dim3(4, 1024 / 4), dim3(64, 4), 0, stream>>>(bufA, s4w0, s4b0, bufB, 1024, 259, 256);
    dense_relu<<<dim3(4, 1024 / 4), dim3(64, 4), 0, stream>>>(bufB, s4w1, s4b1, bufA, 1024, 256, 256);
    max_ns<<<(64 * 256 + 255) / 256, 256, 0, stream>>>(bufA, f4, 64, 16, 256);

    // -------- fp1: xyz3 <- xyz4, [f3 | interp(f4)] 512->256->128 --------
    fp_nn<<<1, 256, 0, stream>>>(xyz3, xyz4, nni1, nnw1, 64, 16);
    interp_concat<<<256 / 4, 256, 0, stream>>>(f3, f4, nni1, nnw1, bufA, 64, 16, 256, 256);
    dense_relu<<<dim3(4, 256 / 4), dim3(64, 4), 0, stream>>>(bufA, p1w0, p1b0, bufB, 256, 512, 256);
    dense_relu<<<dim3(2, 256 / 4), dim3(64, 4), 0, stream>>>(bufB, p1w1, p1b1, f5, 256, 256, 128);

    // -------- fp2: xyz2 <- xyz3, [f2 | interp(f5)] 256->128->64 --------
    fp_nn<<<4, 256, 0, stream>>>(xyz2, xyz3, nni2, nnw2, 256, 64);
    interp_concat<<<1024 / 4, 256, 0, stream>>>(f2, f5, nni2, nnw2, bufA, 256, 64, 128, 128);
    dense_relu<<<dim3(2, 1024 / 4), dim3(64, 4), 0, stream>>>(bufA, p2w0, p2b0, bufB, 1024, 256, 128);
    dense_relu<<<dim3(1, 1024 / 4), dim3(64, 4), 0, stream>>>(bufB, p2w1, p2b1, out, 1024, 128, 64);

    // -------- outputs: [f (4x256x64) | xyz2 (4x256x3)] --------
    copyf<<<12, 256, 0, stream>>>(xyz2, out + 65536, 3072);
}

// Round 14
// 2119.086 us; speedup vs baseline: 1.2451x; 1.0412x over previous
//
#include <hip/hip_runtime.h>
#include <cstddef>

// ---------------- numerics helpers (mirror reference FP32 op order) ----------------

__device__ __forceinline__ float sqd(float x, float y, float z, float qx, float qy, float qz) {
#pragma clang fp contract(off)
    float dx = x - qx, dy = y - qy, dz = z - qz;
    return (dx * dx + dy * dy) + dz * dz;
}

__device__ __forceinline__ float sum3sq(float x, float y, float z) {
#pragma clang fp contract(off)
    return (x * x + y * y) + z * z;
}

// reference _sqdist: sum(a^2) + sum(b^2) - 2*dot(a,b)
__device__ __forceinline__ float sqd_dot(float ax, float ay, float az, float sa_,
                                         float bx, float by, float bz) {
#pragma clang fp contract(off)
    float sb = (bx * bx + by * by) + bz * bz;
    float dt = (ax * bx + ay * by) + az * bz;
    return (sa_ + sb) - 2.0f * dt;
}

// packed argmax key: (float bits of val << 32) | ~orig. mind >= 0 -> monotonic;
// max key == (val desc, orig asc) == reference first-occurrence argmax.
__device__ __forceinline__ unsigned long long packkey(float v, int orig) {
    return ((unsigned long long)__float_as_uint(v) << 32) | (unsigned)(~orig);
}

// ---------------- FPS large (N=32768, npoint=512): bucket pruning, 2 barriers/iter -----
// R6-proven structure with B3 eliminated: every wave redundantly computes the global
// argmax over all 512 cached keys (8 stride-64 LDS reads + 6-step shfl) after B2, so the
// candK/candB round-trip and its barrier disappear. Queue counter is double-buffered
// (qc2[k&1]); the idle slot is reset by t0 between B1 and B2 (ordered before all
// next-iter pushes by B2). bkeyS/bxS phase-3 reads are ordered against next-iter phase-2
// writes by the NEXT B1; curS phase-2 reads vs next-iter phase-1 writes by B2.
// Writes gathered coords directly (xyz1 = selected points, in selection order).

__global__ __launch_bounds__(512) void fps_sub(const float* __restrict__ xyz,
                                               float4* __restrict__ SPall,
                                               float* __restrict__ gout) {
    const int b = blockIdx.x, t = threadIdx.x, w = t >> 6, l = t & 63;
    const float* __restrict__ P = xyz + (size_t)b * 32768 * 3;
    float4* __restrict__ SP = SPall + (size_t)b * 32768;

    __shared__ float mind[32768];
    __shared__ int   cntS[512], offS[512], curS[512];
    __shared__ unsigned long long bkeyS[512];
    __shared__ float bxS[512], byS[512], bzS[512];
    __shared__ float bbS[6];
    __shared__ float scr[48];
    __shared__ int   qc2[2];

    float mnx = 1e30f, mny = 1e30f, mnz = 1e30f;
    float mxx = -1e30f, mxy = -1e30f, mxz = -1e30f;
    for (int p = t; p < 32768; p += 512) {
        const float x = P[3 * p], y = P[3 * p + 1], z = P[3 * p + 2];
        mnx = fminf(mnx, x); mxx = fmaxf(mxx, x);
        mny = fminf(mny, y); mxy = fmaxf(mxy, y);
        mnz = fminf(mnz, z); mxz = fmaxf(mxz, z);
    }
#pragma unroll
    for (int o = 1; o < 64; o <<= 1) {
        mnx = fminf(mnx, __shfl_xor(mnx, o)); mxx = fmaxf(mxx, __shfl_xor(mxx, o));
        mny = fminf(mny, __shfl_xor(mny, o)); mxy = fmaxf(mxy, __shfl_xor(mxy, o));
        mnz = fminf(mnz, __shfl_xor(mnz, o)); mxz = fmaxf(mxz, __shfl_xor(mxz, o));
    }
    if (l == 0) {
        scr[w] = mnx; scr[8 + w] = mny; scr[16 + w] = mnz;
        scr[24 + w] = mxx; scr[32 + w] = mxy; scr[40 + w] = mxz;
    }
    __syncthreads();
    if (t == 0) {
        float a0 = 1e30f, a1 = 1e30f, a2 = 1e30f, a3 = -1e30f, a4 = -1e30f, a5 = -1e30f;
        for (int i = 0; i < 8; ++i) {
            a0 = fminf(a0, scr[i]);      a1 = fminf(a1, scr[8 + i]);
            a2 = fminf(a2, scr[16 + i]); a3 = fmaxf(a3, scr[24 + i]);
            a4 = fmaxf(a4, scr[32 + i]); a5 = fmaxf(a5, scr[40 + i]);
        }
        bbS[0] = a0; bbS[1] = a1; bbS[2] = a2; bbS[3] = a3; bbS[4] = a4; bbS[5] = a5;
        qc2[0] = 0; qc2[1] = 0;
    }
    __syncthreads();
    const float bx0 = bbS[0], by0 = bbS[1], bz0 = bbS[2];
    const float ex = bbS[3] - bx0, ey = bbS[4] - by0, ez = bbS[5] - bz0;
    const float ivx = ex > 1e-20f ? 8.0f / ex : 0.0f;
    const float ivy = ey > 1e-20f ? 8.0f / ey : 0.0f;
    const float ivz = ez > 1e-20f ? 8.0f / ez : 0.0f;

    cntS[t] = 0;
    __syncthreads();
    for (int p = t; p < 32768; p += 512) {
        const float x = P[3 * p], y = P[3 * p + 1], z = P[3 * p + 2];
        const int ix = min(7, (int)((x - bx0) * ivx));
        const int iy = min(7, (int)((y - by0) * ivy));
        const int iz = min(7, (int)((z - bz0) * ivz));
        atomicAdd(&cntS[(iz * 8 + iy) * 8 + ix], 1);
    }
    __syncthreads();

    offS[t] = cntS[t];
    __syncthreads();
    for (int d = 1; d < 512; d <<= 1) {
        const int v = (t >= d) ? offS[t - d] : 0;
        __syncthreads();
        offS[t] += v;
        __syncthreads();
    }
    const int myexc = offS[t] - cntS[t];
    offS[t] = myexc;
    curS[t] = myexc;
    __syncthreads();

    for (int p = t; p < 32768; p += 512) {
        const float x = P[3 * p], y = P[3 * p + 1], z = P[3 * p + 2];
        const int ix = min(7, (int)((x - bx0) * ivx));
        const int iy = min(7, (int)((y - by0) * ivy));
        const int iz = min(7, (int)((z - bz0) * ivz));
        const int pos = atomicAdd(&curS[(iz * 8 + iy) * 8 + ix], 1);
        SP[pos] = make_float4(x, y, z, __int_as_float(p));
    }
    for (int s = t; s < 32768; s += 512) mind[s] = 1e30f;
    const int myCnt = cntS[t];
    bkeyS[t] = (myCnt > 0) ? packkey(1e30f, 0x7fffffff) : 0ull;
    bxS[t] = 0.f; byS[t] = 0.f; bzS[t] = 0.f;
    if (t == 0) {
        gout[(size_t)b * 512 * 3 + 0] = P[0];
        gout[(size_t)b * 512 * 3 + 1] = P[1];
        gout[(size_t)b * 512 * 3 + 2] = P[2];
    }

    const int oix = t & 7, oiy = (t >> 3) & 7, oiz = t >> 6;
    const float gwx = ex * 0.125f, gwy = ey * 0.125f, gwz = ez * 0.125f;
    const float x0o = bx0 + oix * gwx, x1o = x0o + gwx;
    const float y0o = by0 + oiy * gwy, y1o = y0o + gwy;
    const float z0o = bz0 + oiz * gwz, z1o = z0o + gwz;

    const int g  = l >> 4;
    const int lg = l & 15;
    const int sg = w * 4 + g;

    float qx = P[0], qy = P[1], qz = P[2];
    __syncthreads();

    for (int k = 1; k < 512; ++k) {
        // ---- phase 1: test own bucket; wave-aggregated push to qc2[k&1] ----
        const float ddx = fmaxf(fmaxf(x0o - qx, qx - x1o), 0.0f);
        const float ddy = fmaxf(fmaxf(y0o - qy, qy - y1o), 0.0f);
        const float ddz = fmaxf(fmaxf(z0o - qz, qz - z1o), 0.0f);
        const float d2m = (ddx * ddx + ddy * ddy) + ddz * ddz;
        const float bm = __uint_as_float((unsigned)(bkeyS[t] >> 32));
        const bool act = (myCnt > 0) && (d2m <= bm * 1.0001f + 1e-9f);
        const unsigned long long pmask = __ballot(act);
        const int wcnt = __popcll(pmask);
        int wbase = 0;
        if (l == 0 && wcnt) wbase = atomicAdd(&qc2[k & 1], wcnt);
        wbase = __shfl(wbase, 0);
        if (act) curS[wbase + __popcll(pmask & ((1ull << l) - 1ull))] = t;
        __syncthreads();   // B1: queue complete
        const int A = qc2[k & 1];
        if (t == 0) qc2[(k + 1) & 1] = 0;   // idle slot; ordered before next pushes by B2

        // ---- phase 2: process queue entries, 16-lane subgroups ----
        for (int e = sg; e < A; e += 32) {
            const int bu = curS[e];
            const int base = offS[bu], cnt = cntS[bu];
            unsigned long long key = 0ull;
            int klane = l;
            float cx = 0.f, cy = 0.f, cz = 0.f;
            for (int c = lg; c < cnt; c += 16) {
                const float4 pt = SP[base + c];
                const float m = mind[base + c];
                const float d2 = sqd(pt.x, pt.y, pt.z, qx, qy, qz);
                const float nm = fminf(m, d2);
                mind[base + c] = nm;
                const unsigned long long kk = packkey(nm, __float_as_int(pt.w));
                if (kk > key) { key = kk; cx = pt.x; cy = pt.y; cz = pt.z; }
            }
#pragma unroll
            for (int s = 1; s < 16; s <<= 1) {
                const unsigned long long ok = __shfl_xor(key, s);
                const int ol2 = __shfl_xor(klane, s);
                if (ok > key) { key = ok; klane = ol2; }
            }
            const float wx = __shfl(cx, klane), wy = __shfl(cy, klane), wz = __shfl(cz, klane);
            if (lg == 0) {
                bkeyS[bu] = key;
                bxS[bu] = wx; byS[bu] = wy; bzS[bu] = wz;
            }
        }
        __syncthreads();   // B2: caches refreshed

        // ---- phase 3: every wave redundantly computes the global argmax ----
        unsigned long long bk = bkeyS[l];
        int bb = l;
#pragma unroll
        for (int j = 1; j < 8; ++j) {
            const unsigned long long k2 = bkeyS[l + 64 * j];
            if (k2 > bk) { bk = k2; bb = l + 64 * j; }
        }
#pragma unroll
        for (int s = 1; s < 64; s <<= 1) {
            const unsigned long long ok = __shfl_xor(bk, s);
            const int ob = __shfl_xor(bb, s);
            if (ok > bk) { bk = ok; bb = ob; }
        }
        qx = bxS[bb]; qy = byS[bb]; qz = bzS[bb];
        if (t == 0) {
            gout[((size_t)b * 512 + k) * 3 + 0] = qx;
            gout[((size_t)b * 512 + k) * 3 + 1] = qy;
            gout[((size_t)b * 512 + k) * 3 + 2] = qz;
        }
        // phase-3 reads of bkeyS/bxS complete before any thread passes next B1 -> safe
    }
}

// ---------------- FPS, small (N<=512), one wave per batch; writes gathered coords ------

template <int N, int NPOINT>
__global__ __launch_bounds__(64) void fps_small(const float* __restrict__ pts,
                                                float* __restrict__ gout) {
    constexpr int PPT = N / 64;
    const int b = blockIdx.x, l = threadIdx.x;
    const float* __restrict__ P = pts + (size_t)b * N * 3;
    float px[PPT], py[PPT], pz[PPT], md[PPT];
#pragma unroll
    for (int j = 0; j < PPT; ++j) {
        const int p = l + 64 * j;
        px[j] = P[p * 3]; py[j] = P[p * 3 + 1]; pz[j] = P[p * 3 + 2];
        md[j] = 1e30f;
    }
    float qx = P[0], qy = P[1], qz = P[2];
    if (l == 0) {
        gout[(size_t)b * NPOINT * 3 + 0] = qx;
        gout[(size_t)b * NPOINT * 3 + 1] = qy;
        gout[(size_t)b * NPOINT * 3 + 2] = qz;
    }
    for (int k = 1; k < NPOINT; ++k) {
        float bv = -1.0f;
        int   bi = 0;
#pragma unroll
        for (int j = 0; j < PPT; ++j) {
            md[j] = fminf(md[j], sqd(px[j], py[j], pz[j], qx, qy, qz));
            if (md[j] > bv) { bv = md[j]; bi = l + 64 * j; }
        }
#pragma unroll
        for (int off = 1; off < 64; off <<= 1) {
            float ov = __shfl_xor(bv, off);
            int   oi = __shfl_xor(bi, off);
            if (ov > bv || (ov == bv && oi < bi)) { bv = ov; bi = oi; }
        }
        const int ol = bi & 63, js = bi >> 6;
        float sx = px[0], sy = py[0], sz = pz[0];
#pragma unroll
        for (int j = 1; j < PPT; ++j) {
            if (j == js) { sx = px[j]; sy = py[j]; sz = pz[j]; }
        }
        qx = __shfl(sx, ol); qy = __shfl(sy, ol); qz = __shfl(sz, ol);
        if (l == 0) {
            gout[((size_t)b * NPOINT + k) * 3 + 0] = qx;
            gout[((size_t)b * NPOINT + k) * 3 + 1] = qy;
            gout[((size_t)b * NPOINT + k) * 3 + 2] = qz;
        }
    }
}

// ---------------- ball query: first NS points with d2 < r2, pad with first hit ---------

template <int NS>
__global__ __launch_bounds__(256) void ball_query_k(const float* __restrict__ xyz,
                                                    const float* __restrict__ centers,
                                                    int* __restrict__ out,
                                                    int N, int M, float r2) {
    const int wv = blockIdx.x * 4 + (threadIdx.x >> 6);
    const int l  = threadIdx.x & 63;
    const int b  = wv / M;
    const float* cp = centers + (size_t)wv * 3;
    const float ax = cp[0], ay = cp[1], az = cp[2];
    const float sa_ = sum3sq(ax, ay, az);
    const float* __restrict__ P = xyz + (size_t)b * N * 3;
    int* o = out + (size_t)wv * NS;

    int cnt = 0, first = -1;
    float nx = P[l * 3], ny = P[l * 3 + 1], nz = P[l * 3 + 2];
    for (int i0 = 0; i0 < N; i0 += 64) {
        const float bx = nx, by = ny, bz = nz;
        if (i0 + 64 < N) {
            const int ip = (i0 + 64 + l) * 3;
            nx = P[ip]; ny = P[ip + 1]; nz = P[ip + 2];
        }
        const float d2 = sqd_dot(ax, ay, az, sa_, bx, by, bz);
        const bool in = d2 < r2;
        const unsigned long long mask = __ballot(in);
        if (first < 0 && mask != 0ull) first = i0 + __builtin_ctzll(mask);
        const int pos = cnt + __popcll(mask & ((1ull << l) - 1ull));
        if (in && pos < NS) o[pos] = i0 + l;
        cnt += __popcll(mask);
        if (cnt >= NS) break;
    }
    if (first < 0) first = 0;
    for (int p2 = cnt + l; p2 < NS; p2 += 64) o[p2] = first;
}

// ---------------- fused SA for sa1: gather + normalize + 3-layer MLP + max ----------------

template <int NS, int CF, int C1, int C2, int C3>
__global__ __launch_bounds__(64) void sa_fused(
    const float* __restrict__ xyz, const float* __restrict__ feats,
    const float* __restrict__ centers, const int* __restrict__ idx,
    const float* __restrict__ w0, const float* __restrict__ b0,
    const float* __restrict__ w1, const float* __restrict__ b1,
    const float* __restrict__ w2, const float* __restrict__ b2,
    float* __restrict__ outf, int N, int M, float r) {
    constexpr int CIN = 3 + CF;
    constexpr int CL  = (C3 > 0) ? C3 : C2;
    constexpr int CPB = 64 / NS;
    const int tid = threadIdx.x;
    const int ci = tid / NS, s = tid % NS;
    const int gc = blockIdx.x * CPB + ci;
    const int b  = gc / M;
    const float* cp = centers + (size_t)gc * 3;
    const float cx = cp[0], cy = cp[1], cz = cp[2];
    const int n = idx[(size_t)gc * NS + s];
    const float* pp = xyz + ((size_t)b * N + n) * 3;
    float gi[CIN];
    gi[0] = (pp[0] - cx) / r; gi[1] = (pp[1] - cy) / r; gi[2] = (pp[2] - cz) / r;
    if constexpr (CF > 0) {
        const float* fr = feats + ((size_t)b * N + n) * CF;
#pragma unroll
        for (int c = 0; c < CF; ++c) gi[3 + c] = fr[c];
    }
    float h1[C1];
#pragma unroll
    for (int o = 0; o < C1; ++o) {
        float acc = b0[o];
#pragma unroll
        for (int k = 0; k < CIN; ++k) acc += gi[k] * w0[k * C1 + o];
        h1[o] = fmaxf(acc, 0.f);
    }
    float h2[C2];
#pragma unroll
    for (int o = 0; o < C2; ++o) {
        float acc = b1[o];
#pragma unroll
        for (int k = 0; k < C1; ++k) acc += h1[k] * w1[k * C2 + o];
        h2[o] = fmaxf(acc, 0.f);
    }
    float hl[CL];
    if constexpr (C3 > 0) {
#pragma unroll
        for (int o = 0; o < C3; ++o) {
            float acc = b2[o];
#pragma unroll
            for (int k = 0; k < C2; ++k) acc += h2[k] * w2[k * C3 + o];
            hl[o] = fmaxf(acc, 0.f);
        }
    } else {
#pragma unroll
        for (int o = 0; o < CL; ++o) hl[o] = h2[o];
    }
    __shared__ float hs[64][CL + 1];
#pragma unroll
    for (int c = 0; c < CL; ++c) hs[tid][c] = hl[c];
    __syncthreads();
    for (int cc = 0; cc < CPB; ++cc) {
        for (int c = tid; c < CL; c += 64) {
            float mx = hs[cc * NS][c];
            for (int s2 = 1; s2 < NS; ++s2) mx = fmaxf(mx, hs[cc * NS + s2][c]);
            outf[(size_t)(blockIdx.x * CPB + cc) * CL + c] = mx;
        }
    }
}

// ---------------- build grouped input rows: [(p-c)/r | feats[n]] ----------------

__global__ void build_g(const float* __restrict__ xyz, const float* __restrict__ feats,
                        const float* __restrict__ centers, const int* __restrict__ idx,
                        float* __restrict__ g, int N, int M, int NS, int CF, float r) {
    const int row = blockIdx.x * 4 + (threadIdx.x >> 6);
    const int l   = threadIdx.x & 63;
    const int gc  = row / NS;
    const int b   = gc / M;
    const int n   = idx[row];
    const float* cp = centers + (size_t)gc * 3;
    const float* pp = xyz + ((size_t)b * N + n) * 3;
    float* go = g + (size_t)row * (3 + CF);
    if (l < 3) go[l] = (pp[l] - cp[l]) / r;
    for (int c = l; c < CF; c += 64) go[3 + c] = feats[((size_t)b * N + n) * CF + c];
}

// ---------------- dense layer + relu ----------------

__global__ void dense_relu(const float* __restrict__ X, const float* __restrict__ Wm,
                           const float* __restrict__ bias, float* __restrict__ Y,
                           int M, int CI, int CO) {
    const int co = blockIdx.x * 64 + threadIdx.x;
    const int m  = blockIdx.y * 4 + threadIdx.y;
    const float* x = X + (size_t)m * CI;
    float acc = bias[co];
#pragma unroll 4
    for (int k = 0; k < CI; ++k) acc += x[k] * Wm[(size_t)k * CO + co];
    Y[(size_t)m * CO + co] = fmaxf(acc, 0.f);
}

// ---------------- max over samples ----------------

__global__ void max_ns(const float* __restrict__ H, float* __restrict__ F,
                       int BM, int NS, int C) {
    const int tid = blockIdx.x * 256 + threadIdx.x;
    if (tid >= BM * C) return;
    const int bm = tid / C, c = tid % C;
    const float* h = H + ((size_t)bm * NS) * C + c;
    float mx = h[0];
    for (int s = 1; s < NS; ++s) mx = fmaxf(mx, h[(size_t)s * C]);
    F[tid] = mx;
}

// ---------------- FP: 3-NN + inverse-distance weights ----------------

__global__ void fp_nn(const float* __restrict__ unk, const float* __restrict__ kn,
                      int* __restrict__ nni, float* __restrict__ nnw, int NU, int NK) {
    const int t = blockIdx.x * blockDim.x + threadIdx.x;
    const int b = t / NU;
    const float* u = unk + (size_t)t * 3;
    const float ax = u[0], ay = u[1], az = u[2];
    const float sa_ = sum3sq(ax, ay, az);
    const float* K = kn + (size_t)b * NK * 3;
    float v0 = 1e30f, v1 = 1e30f, v2 = 1e30f;
    int   j0 = 0, j1 = 0, j2 = 0;
    for (int k = 0; k < NK; ++k) {
        const float d2 = sqd_dot(ax, ay, az, sa_, K[k * 3], K[k * 3 + 1], K[k * 3 + 2]);
        if (d2 < v0)      { v2 = v1; j2 = j1; v1 = v0; j1 = j0; v0 = d2; j0 = k; }
        else if (d2 < v1) { v2 = v1; j2 = j1; v1 = d2; j1 = k; }
        else if (d2 < v2) { v2 = d2; j2 = k; }
    }
    const float d0 = fmaxf(v0, 0.f), d1 = fmaxf(v1, 0.f), dd2 = fmaxf(v2, 0.f);
    float w0 = 1.f / (d0 + 1e-8f), w1 = 1.f / (d1 + 1e-8f), w2 = 1.f / (dd2 + 1e-8f);
    const float s = (w0 + w1) + w2;
    nnw[t * 3] = w0 / s; nnw[t * 3 + 1] = w1 / s; nnw[t * 3 + 2] = w2 / s;
    nni[t * 3] = j0; nni[t * 3 + 1] = j1; nni[t * 3 + 2] = j2;
}

// ---------------- FP: concat [feats1 | interp(feats2)] ----------------

__global__ void interp_concat(const float* __restrict__ f1, const float* __restrict__ f2,
                              const int* __restrict__ nni, const float* __restrict__ nnw,
                              float* __restrict__ X, int NU, int NK, int C1c, int C2c) {
    const int row = blockIdx.x * 4 + (threadIdx.x >> 6);
    const int l   = threadIdx.x & 63;
    const int b   = row / NU;
    const int i0 = nni[row * 3], i1 = nni[row * 3 + 1], i2 = nni[row * 3 + 2];
    const float w0 = nnw[row * 3], w1 = nnw[row * 3 + 1], w2 = nnw[row * 3 + 2];
    float* xo = X + (size_t)row * (C1c + C2c);
    for (int c = l; c < C1c; c += 64) xo[c] = f1[(size_t)row * C1c + c];
    const float* a  = f2 + ((size_t)b * NK + i0) * C2c;
    const float* bb = f2 + ((size_t)b * NK + i1) * C2c;
    const float* cc = f2 + ((size_t)b * NK + i2) * C2c;
    for (int c = l; c < C2c; c += 64) xo[C1c + c] = (w0 * a[c] + w1 * bb[c]) + w2 * cc[c];
}

__global__ void copyf(const float* __restrict__ src, float* __restrict__ dst, int n) {
    const int i = blockIdx.x * 256 + threadIdx.x;
    if (i < n) dst[i] = src[i];
}

// ---------------- host launcher ----------------

extern "C" void kernel_launch(void* const* d_in, const int* in_sizes, int n_in,
                              void* d_out, int out_size, void* d_ws, size_t ws_size,
                              hipStream_t stream) {
    const float* xyz  = (const float*)d_in[0];
    const float* s1w0 = (const float*)d_in[1],  *s1b0 = (const float*)d_in[2];
    const float* s1w1 = (const float*)d_in[3],  *s1b1 = (const float*)d_in[4];
    const float* s1w2 = (const float*)d_in[5],  *s1b2 = (const float*)d_in[6];
    const float* s2w0 = (const float*)d_in[7],  *s2b0 = (const float*)d_in[8];
    const float* s2w1 = (const float*)d_in[9],  *s2b1 = (const float*)d_in[10];
    const float* s3w0 = (const float*)d_in[11], *s3b0 = (const float*)d_in[12];
    const float* s3w1 = (const float*)d_in[13], *s3b1 = (const float*)d_in[14];
    const float* s4w0 = (const float*)d_in[15], *s4b0 = (const float*)d_in[16];
    const float* s4w1 = (const float*)d_in[17], *s4b1 = (const float*)d_in[18];
    const float* p1w0 = (const float*)d_in[19], *p1b0 = (const float*)d_in[20];
    const float* p1w1 = (const float*)d_in[21], *p1b1 = (const float*)d_in[22];
    const float* p2w0 = (const float*)d_in[23], *p2b0 = (const float*)d_in[24];
    const float* p2w1 = (const float*)d_in[25], *p2b1 = (const float*)d_in[26];
    float* out = (float*)d_out;
    float* W = (float*)d_ws;

    size_t off = 0;
    auto A_ = [&](size_t n) { size_t o = off; off += (n + 63) & ~(size_t)63; return o; };
    const size_t o_xyz1  = A_(4 * 512 * 3);
    const size_t o_idx1  = A_(4 * 512 * 64);
    const size_t o_f1    = A_(4 * 512 * 64);
    const size_t o_xyz2  = A_(4 * 256 * 3);
    const size_t o_idx2  = A_(4 * 256 * 32);
    const size_t o_f2    = A_(4 * 256 * 128);
    const size_t o_xyz3  = A_(4 * 64 * 3);
    const size_t o_idx3  = A_(4 * 64 * 16);
    const size_t o_f3    = A_(4 * 64 * 256);
    const size_t o_xyz4  = A_(4 * 16 * 3);
    const size_t o_idx4  = A_(4 * 16 * 16);
    const size_t o_f4    = A_(4 * 16 * 256);
    const size_t o_f5    = A_(4 * 64 * 128);
    const size_t o_nni1  = A_(4 * 64 * 3);
    const size_t o_nnw1  = A_(4 * 64 * 3);
    const size_t o_nni2  = A_(4 * 256 * 3);
    const size_t o_nnw2  = A_(4 * 256 * 3);
    const size_t o_sort  = A_((size_t)4 * 32768 * 4);  // float4 sorted points
    const size_t o_bufA  = A_((size_t)32768 * 128);    // 16 MiB arena
    const size_t o_bufB  = A_((size_t)32768 * 64);     //  8 MiB arena
    if (off * sizeof(float) > ws_size) return;  // fail loudly (validation will catch)

    float* xyz1  = W + o_xyz1;
    int*   idx1  = (int*)(W + o_idx1);  float* f1   = W + o_f1;
    float* xyz2  = W + o_xyz2;
    int*   idx2  = (int*)(W + o_idx2);  float* f2   = W + o_f2;
    float* xyz3  = W + o_xyz3;
    int*   idx3  = (int*)(W + o_idx3);  float* f3   = W + o_f3;
    float* xyz4  = W + o_xyz4;
    int*   idx4  = (int*)(W + o_idx4);  float* f4   = W + o_f4;
    float* f5    = W + o_f5;
    int*   nni1  = (int*)(W + o_nni1);  float* nnw1 = W + o_nnw1;
    int*   nni2  = (int*)(W + o_nni2);  float* nnw2 = W + o_nnw2;
    float4* sortP = (float4*)(W + o_sort);
    float* bufA  = W + o_bufA;
    float* bufB  = W + o_bufB;

    // -------- sa1: npoint=512, r=0.1, ns=64, MLP 3->32->32->64 --------
    fps_sub<<<4, 512, 0, stream>>>(xyz, sortP, xyz1);
    ball_query_k<64><<<512, 256, 0, stream>>>(xyz, xyz1, idx1, 32768, 512, (float)(0.1 * 0.1));
    sa_fused<64, 0, 32, 32, 64><<<2048, 64, 0, stream>>>(
        xyz, nullptr, xyz1, idx1, s1w0, s1b0, s1w1, s1b1, s1w2, s1b2, f1, 32768, 512, 0.1f);

    // -------- sa2: npoint=256, r=0.2, ns=32, MLP 67->64->128 --------
    fps_small<512, 256><<<4, 64, 0, stream>>>(xyz1, xyz2);
    ball_query_k<32><<<256, 256, 0, stream>>>(xyz1, xyz2, idx2, 512, 256, (float)(0.2 * 0.2));
    build_g<<<32768 / 4, 256, 0, stream>>>(xyz1, f1, xyz2, idx2, bufA, 512, 256, 32, 64, 0.2f);
    dense_relu<<<dim3(1, 32768 / 4), dim3(64, 4), 0, stream>>>(bufA, s2w0, s2b0, bufB, 32768, 67, 64);
    dense_relu<<<dim3(2, 32768 / 4), dim3(64, 4), 0, stream>>>(bufB, s2w1, s2b1, bufA, 32768, 64, 128);
    max_ns<<<(1024 * 128 + 255) / 256, 256, 0, stream>>>(bufA, f2, 1024, 32, 128);

    // -------- sa3: npoint=64, r=0.4, ns=16, MLP 131->128->256 --------
    fps_small<256, 64><<<4, 64, 0, stream>>>(xyz2, xyz3);
    ball_query_k<16><<<64, 256, 0, stream>>>(xyz2, xyz3, idx3, 256, 64, (float)(0.4 * 0.4));
    build_g<<<4096 / 4, 256, 0, stream>>>(xyz2, f2, xyz3, idx3, bufA, 256, 64, 16, 128, 0.4f);
    dense_relu<<<dim3(2, 4096 / 4), dim3(64, 4), 0, stream>>>(bufA, s3w0, s3b0, bufB, 4096, 131, 128);
    dense_relu<<<dim3(4, 4096 / 4), dim3(64, 4), 0, stream>>>(bufB, s3w1, s3b1, bufA, 4096, 128, 256);
    max_ns<<<(256 * 256 + 255) / 256, 256, 0, stream>>>(bufA, f3, 256, 16, 256);

    // -------- sa4: npoint=16, r=0.8, ns=16, MLP 259->256->256 --------
    fps_small<64, 16><<<4, 64, 0, stream>>>(xyz3, xyz4);
    ball_query_k<16><<<16, 256, 0, stream>>>(xyz3, xyz4, idx4, 64, 16, (float)(0.8 * 0.8));
    build_g<<<1024 / 4, 256, 0, stream>>>(xyz3, f3, xyz4, idx4, bufA, 64, 16, 16, 256, 0.8f);
    dense_relu<<<dim3(4, 1024 / 4), dim3(64, 4), 0, stream>>>(bufA, s4w0, s4b0, bufB, 1024, 259, 256);
    dense_relu<<<dim3(4, 1024 / 4), dim3(64, 4), 0, stream>>>(bufB, s4w1, s4b1, bufA, 1024, 256, 256);
    max_ns<<<(64 * 256 + 255) / 256, 256, 0, stream>>>(bufA, f4, 64, 16, 256);

    // -------- fp1: xyz3 <- xyz4, [f3 | interp(f4)] 512->256->128 --------
    fp_nn<<<1, 256, 0, stream>>>(xyz3, xyz4, nni1, nnw1, 64, 16);
    interp_concat<<<256 / 4, 256, 0, stream>>>(f3, f4, nni1, nnw1, bufA, 64, 16, 256, 256);
    dense_relu<<<dim3(4, 256 / 4), dim3(64, 4), 0, stream>>>(bufA, p1w0, p1b0, bufB, 256, 512, 256);
    dense_relu<<<dim3(2, 256 / 4), dim3(64, 4), 0, stream>>>(bufB, p1w1, p1b1, f5, 256, 256, 128);

    // -------- fp2: xyz2 <- xyz3, [f2 | interp(f5)] 256->128->64 --------
    fp_nn<<<4, 256, 0, stream>>>(xyz2, xyz3, nni2, nnw2, 256, 64);
    interp_concat<<<1024 / 4, 256, 0, stream>>>(f2, f5, nni2, nnw2, bufA, 256, 64, 128, 128);
    dense_relu<<<dim3(2, 1024 / 4), dim3(64, 4), 0, stream>>>(bufA, p2w0, p2b0, bufB, 1024, 256, 128);
    dense_relu<<<dim3(1, 1024 / 4), dim3(64, 4), 0, stream>>>(bufB, p2w1, p2b1, out, 1024, 128, 64);

    // -------- outputs: [f (4x256x64) | xyz2 (4x256x3)] --------
    copyf<<<12, 256, 0, stream>>>(xyz2, out + 65536, 3072);
}